// Round 5
// baseline (519.035 us; speedup 1.0000x reference)
//
#include <hip/hip_runtime.h>

#define N_LOC   500000
#define N_CAT   5000
#define N_EDGES 2000000
#define DIM     128
#define NEG_SLOPE 0.2f
#define PAD     5008
#define NB      64
#define EPB     31252   // ceil(N_EDGES/NB) rounded up to multiple of 4

// ================= K1: per-block LDS histogram (+ fused W transpose) =================
__launch_bounds__(1024)
__global__ void blockhist_kernel(const int* __restrict__ edst, const float* __restrict__ W,
                                 float* __restrict__ WT, int* __restrict__ rank,
                                 int* __restrict__ bhist) {
    int b = blockIdx.x, t = threadIdx.x;
    if (b == NB) {  // transpose W -> WT
        for (int i = t; i < DIM * DIM; i += 1024) {
            int j = i >> 7, k = i & 127;
            WT[k * DIM + j] = W[j * DIM + k];
        }
        return;
    }
    __shared__ int lh[N_CAT];
    for (int c = t; c < N_CAT; c += 1024) lh[c] = 0;
    __syncthreads();
    int s = b * EPB;
    int e = min(s + EPB, N_EDGES);
    int i = s + 4 * t;
    for (; i + 4 <= e; i += 4096) {
        int4 d = *(const int4*)(edst + i);
        int4 r;
        r.x = atomicAdd(&lh[d.x], 1);
        r.y = atomicAdd(&lh[d.y], 1);
        r.z = atomicAdd(&lh[d.z], 1);
        r.w = atomicAdd(&lh[d.w], 1);
        *(int4*)(rank + i) = r;
    }
    if (i < e) {
        int lim = min(i + 4, e);
        for (int j = i; j < lim; ++j) rank[j] = atomicAdd(&lh[edst[j]], 1);
    }
    __syncthreads();
    for (int c = t; c < N_CAT; c += 1024)
        bhist[(size_t)b * N_CAT + c] = lh[c];
}

// ================= K2: fused per-cat block-prefix + global offsets scan (single block) ======
__launch_bounds__(1024)
__global__ void fused_scan_kernel(int* __restrict__ bhist, int* __restrict__ offsets) {
    __shared__ int stot[N_CAT];
    __shared__ int wsum[16];
    __shared__ int woff[16];
    __shared__ int total_s, running_s;
    int t = threadIdx.x;
    int runs[5] = {0, 0, 0, 0, 0};
    int cur[5], nxt[5];
    #pragma unroll
    for (int k = 0; k < 5; ++k) {
        int c = t + 1024 * k;
        cur[k] = (c < N_CAT) ? bhist[c] : 0;
    }
    for (int b = 0; b < NB; ++b) {
        size_t base = (size_t)b * N_CAT;
        if (b + 1 < NB) {
            size_t nb = base + N_CAT;
            #pragma unroll
            for (int k = 0; k < 5; ++k) {
                int c = t + 1024 * k;
                nxt[k] = (c < N_CAT) ? bhist[nb + c] : 0;
            }
        }
        #pragma unroll
        for (int k = 0; k < 5; ++k) {
            int c = t + 1024 * k;
            if (c < N_CAT) bhist[base + c] = runs[k];
            runs[k] += cur[k];
            cur[k] = nxt[k];
        }
    }
    #pragma unroll
    for (int k = 0; k < 5; ++k) {
        int c = t + 1024 * k;
        if (c < N_CAT) stot[c] = runs[k];
    }
    if (t == 0) { running_s = 0; offsets[0] = 0; }
    __syncthreads();
    int lane = t & 63, w = t >> 6;
    for (int base2 = 0; base2 < N_CAT; base2 += 1024) {
        int i2 = base2 + t;
        int v = (i2 < N_CAT) ? stot[i2] : 0;
        int incl = v;
        #pragma unroll
        for (int off = 1; off < 64; off <<= 1) {
            int x = __shfl_up(incl, off, 64);
            if (lane >= off) incl += x;
        }
        if (lane == 63) wsum[w] = incl;
        __syncthreads();
        if (w == 0 && lane < 16) {
            int s = wsum[lane];
            int e = s;
            #pragma unroll
            for (int off = 1; off < 16; off <<= 1) {
                int x = __shfl_up(e, off, 64);
                if (lane >= off) e += x;
            }
            woff[lane] = e - s;
            if (lane == 15) total_s = e;
        }
        __syncthreads();
        int run = running_s;
        if (i2 < N_CAT) offsets[i2 + 1] = run + woff[w] + incl;
        __syncthreads();
        if (t == 0) running_s = run + total_s;
        __syncthreads();
    }
}

// ================= K3: atomic-free scatter fill (int4-vectorized) =================
__global__ void fill2_kernel(const int* __restrict__ esrc, const int* __restrict__ edst,
                             const int* __restrict__ rank, const int* __restrict__ offsets,
                             const int* __restrict__ bhist, int* __restrict__ csr_src) {
    int i4 = (blockIdx.x * blockDim.x + threadIdx.x) * 4;
    if (i4 + 4 <= N_EDGES) {
        int4 c = *(const int4*)(edst + i4);
        int4 s = *(const int4*)(esrc + i4);
        int4 r = *(const int4*)(rank + i4);
        size_t bb = (size_t)(i4 / EPB) * N_CAT;   // EPB mult of 4: chunk never straddles
        csr_src[offsets[c.x] + bhist[bb + c.x] + r.x] = s.x;
        csr_src[offsets[c.y] + bhist[bb + c.y] + r.y] = s.y;
        csr_src[offsets[c.z] + bhist[bb + c.z] + r.z] = s.z;
        csr_src[offsets[c.w] + bhist[bb + c.w] + r.w] = s.w;
    } else {
        for (int i = i4; i < N_EDGES; ++i) {
            int c = edst[i];
            size_t bb = (size_t)(i / EPB) * N_CAT;
            csr_src[offsets[c] + bhist[bb + c] + rank[i]] = esrc[i];
        }
    }
}

// ================= K4: fused aggregate + linear + LeakyReLU =================
// one block per cat; 8 groups x 32 lanes; contiguous csr range per group, unroll x8.
__launch_bounds__(256)
__global__ void agg_fused_kernel(const float* __restrict__ loc, const int* __restrict__ csr_src,
                                 const int* __restrict__ offsets, const float* __restrict__ WT,
                                 const float* __restrict__ bias, float* __restrict__ out) {
    __shared__ float4 sacc[256];   // reused as float sred[1024]
    __shared__ float  srow[DIM];
    int c = blockIdx.x;
    int t = threadIdx.x;
    int g = t >> 5;
    int l = t & 31;
    int beg = offsets[c];
    int end = offsets[c + 1];
    int cnt = end - beg;
    int per = (cnt + 7) >> 3;
    int gbeg = beg + g * per;
    int gend = min(gbeg + per, end);

    float4 a0 = make_float4(0.f, 0.f, 0.f, 0.f);
    float4 a1 = make_float4(0.f, 0.f, 0.f, 0.f);
    float4 a2 = make_float4(0.f, 0.f, 0.f, 0.f);
    float4 a3 = make_float4(0.f, 0.f, 0.f, 0.f);
    int e = gbeg;
    for (; e + 8 <= gend; e += 8) {
        int s0 = csr_src[e + 0], s1 = csr_src[e + 1], s2 = csr_src[e + 2], s3 = csr_src[e + 3];
        int s4 = csr_src[e + 4], s5 = csr_src[e + 5], s6 = csr_src[e + 6], s7 = csr_src[e + 7];
        float4 v0 = ((const float4*)(loc + (size_t)s0 * DIM))[l];
        float4 v1 = ((const float4*)(loc + (size_t)s1 * DIM))[l];
        float4 v2 = ((const float4*)(loc + (size_t)s2 * DIM))[l];
        float4 v3 = ((const float4*)(loc + (size_t)s3 * DIM))[l];
        float4 v4 = ((const float4*)(loc + (size_t)s4 * DIM))[l];
        float4 v5 = ((const float4*)(loc + (size_t)s5 * DIM))[l];
        float4 v6 = ((const float4*)(loc + (size_t)s6 * DIM))[l];
        float4 v7 = ((const float4*)(loc + (size_t)s7 * DIM))[l];
        a0.x += v0.x; a0.y += v0.y; a0.z += v0.z; a0.w += v0.w;
        a1.x += v1.x; a1.y += v1.y; a1.z += v1.z; a1.w += v1.w;
        a2.x += v2.x; a2.y += v2.y; a2.z += v2.z; a2.w += v2.w;
        a3.x += v3.x; a3.y += v3.y; a3.z += v3.z; a3.w += v3.w;
        a0.x += v4.x; a0.y += v4.y; a0.z += v4.z; a0.w += v4.w;
        a1.x += v5.x; a1.y += v5.y; a1.z += v5.z; a1.w += v5.w;
        a2.x += v6.x; a2.y += v6.y; a2.z += v6.z; a2.w += v6.w;
        a3.x += v7.x; a3.y += v7.y; a3.z += v7.z; a3.w += v7.w;
    }
    for (; e + 4 <= gend; e += 4) {
        int s0 = csr_src[e + 0], s1 = csr_src[e + 1], s2 = csr_src[e + 2], s3 = csr_src[e + 3];
        float4 v0 = ((const float4*)(loc + (size_t)s0 * DIM))[l];
        float4 v1 = ((const float4*)(loc + (size_t)s1 * DIM))[l];
        float4 v2 = ((const float4*)(loc + (size_t)s2 * DIM))[l];
        float4 v3 = ((const float4*)(loc + (size_t)s3 * DIM))[l];
        a0.x += v0.x; a0.y += v0.y; a0.z += v0.z; a0.w += v0.w;
        a1.x += v1.x; a1.y += v1.y; a1.z += v1.z; a1.w += v1.w;
        a2.x += v2.x; a2.y += v2.y; a2.z += v2.z; a2.w += v2.w;
        a3.x += v3.x; a3.y += v3.y; a3.z += v3.z; a3.w += v3.w;
    }
    for (; e < gend; ++e) {
        int s = csr_src[e];
        float4 v = ((const float4*)(loc + (size_t)s * DIM))[l];
        a0.x += v.x; a0.y += v.y; a0.z += v.z; a0.w += v.w;
    }
    float4 acc = make_float4((a0.x + a1.x) + (a2.x + a3.x),
                             (a0.y + a1.y) + (a2.y + a3.y),
                             (a0.z + a1.z) + (a2.z + a3.z),
                             (a0.w + a1.w) + (a2.w + a3.w));
    sacc[t] = acc;
    __syncthreads();
    if (t < 128) {
        float4 a = sacc[t], b = sacc[t + 128];
        sacc[t] = make_float4(a.x + b.x, a.y + b.y, a.z + b.z, a.w + b.w);
    }
    __syncthreads();
    if (t < 64) {
        float4 a = sacc[t], b = sacc[t + 64];
        sacc[t] = make_float4(a.x + b.x, a.y + b.y, a.z + b.z, a.w + b.w);
    }
    __syncthreads();
    if (t < 32) {
        float4 a = sacc[t], b = sacc[t + 32];
        srow[4 * t + 0] = a.x + b.x;
        srow[4 * t + 1] = a.y + b.y;
        srow[4 * t + 2] = a.z + b.z;
        srow[4 * t + 3] = a.w + b.w;
    }
    __syncthreads();
    int j = t & 127;
    int h = t >> 7;
    float m0 = 0.f, m1 = 0.f, m2 = 0.f, m3 = 0.f;
    int k0 = h * 64;
    #pragma unroll 4
    for (int k = 0; k < 64; k += 4) {
        m0 += WT[(k0 + k + 0) * DIM + j] * srow[k0 + k + 0];
        m1 += WT[(k0 + k + 1) * DIM + j] * srow[k0 + k + 1];
        m2 += WT[(k0 + k + 2) * DIM + j] * srow[k0 + k + 2];
        m3 += WT[(k0 + k + 3) * DIM + j] * srow[k0 + k + 3];
    }
    float* sred = (float*)sacc;
    sred[t] = (m0 + m1) + (m2 + m3);
    __syncthreads();
    if (t < 128) {
        float v = sred[t] + sred[t + 128] + bias[t];
        v = v > 0.f ? v : NEG_SLOPE * v;
        out[(size_t)c * DIM + t] = v;
    }
}

// ================= fallback paths =================

__global__ void hist_rank_kernel(const int* __restrict__ dst, int* __restrict__ cnt,
                                 int* __restrict__ rank, int n) {
    int i = blockIdx.x * blockDim.x + threadIdx.x;
    if (i < n) rank[i] = atomicAdd(&cnt[dst[i]], 1);
}

__global__ void fill_rank_kernel(const int* __restrict__ src, const int* __restrict__ dst,
                                 const int* __restrict__ rank, const int* __restrict__ offsets,
                                 int* __restrict__ csr_src, int n) {
    int i = blockIdx.x * blockDim.x + threadIdx.x;
    if (i < n) csr_src[offsets[dst[i]] + rank[i]] = src[i];
}

__launch_bounds__(1024)
__global__ void scan_kernel(const int* __restrict__ cnt, int* __restrict__ offsets) {
    __shared__ int wsum[16];
    __shared__ int woff[16];
    __shared__ int total_s, running_s;
    int t = threadIdx.x;
    int lane = t & 63, w = t >> 6;
    if (t == 0) { running_s = 0; offsets[0] = 0; }
    __syncthreads();
    for (int base = 0; base < N_CAT; base += 1024) {
        int i = base + t;
        int v = (i < N_CAT) ? cnt[i] : 0;
        int incl = v;
        #pragma unroll
        for (int off = 1; off < 64; off <<= 1) {
            int x = __shfl_up(incl, off, 64);
            if (lane >= off) incl += x;
        }
        if (lane == 63) wsum[w] = incl;
        __syncthreads();
        if (w == 0 && lane < 16) {
            int s = wsum[lane];
            int e = s;
            #pragma unroll
            for (int off = 1; off < 16; off <<= 1) {
                int x = __shfl_up(e, off, 64);
                if (lane >= off) e += x;
            }
            woff[lane] = e - s;
            if (lane == 15) total_s = e;
        }
        __syncthreads();
        int run = running_s;
        if (i < N_CAT) offsets[i + 1] = run + woff[w] + incl;
        __syncthreads();
        if (t == 0) running_s = run + total_s;
        __syncthreads();
    }
}

__global__ void transpose_kernel(const float* __restrict__ W, float* __restrict__ WT) {
    int j = blockIdx.x;
    int k = threadIdx.x;
    WT[k * DIM + j] = W[j * DIM + k];
}

__global__ void zero_kernel(float* p, int n) {
    int i = blockIdx.x * blockDim.x + threadIdx.x;
    if (i < n) p[i] = 0.f;
}

__launch_bounds__(128)
__global__ void scatter_atomic_kernel(const float* __restrict__ loc, const int* __restrict__ src,
                                      const int* __restrict__ dst, float* __restrict__ agg) {
    int e = blockIdx.x;
    int d = threadIdx.x;
    atomicAdd(&agg[(size_t)dst[e] * DIM + d], loc[(size_t)src[e] * DIM + d]);
}

#define CATS_PER_BLOCK 8
__launch_bounds__(256)
__global__ void gemm_lrelu_kernel(const float* __restrict__ agg, const float* __restrict__ W,
                                  const float* __restrict__ b, float* __restrict__ out) {
    __shared__ float sW[DIM * 129];
    __shared__ float sA[CATS_PER_BLOCK * DIM];
    int t = threadIdx.x;
    int cbase = blockIdx.x * CATS_PER_BLOCK;
    for (int i = t; i < DIM * DIM; i += 256) {
        int j = i >> 7, k = i & 127;
        sW[j * 129 + k] = W[i];
    }
    for (int i = t; i < CATS_PER_BLOCK * DIM; i += 256)
        sA[i] = agg[(size_t)cbase * DIM + i];
    __syncthreads();
    int j = t & 127;
    int cc = t >> 7;
    float acc0 = 0.f, acc1 = 0.f, acc2 = 0.f, acc3 = 0.f;
    for (int k = 0; k < DIM; ++k) {
        float w = sW[j * 129 + k];
        acc0 += w * sA[(cc + 0) * DIM + k];
        acc1 += w * sA[(cc + 2) * DIM + k];
        acc2 += w * sA[(cc + 4) * DIM + k];
        acc3 += w * sA[(cc + 6) * DIM + k];
    }
    float bj = b[j];
    float r0 = acc0 + bj, r1 = acc1 + bj, r2 = acc2 + bj, r3 = acc3 + bj;
    r0 = r0 > 0.f ? r0 : NEG_SLOPE * r0;
    r1 = r1 > 0.f ? r1 : NEG_SLOPE * r1;
    r2 = r2 > 0.f ? r2 : NEG_SLOPE * r2;
    r3 = r3 > 0.f ? r3 : NEG_SLOPE * r3;
    out[(size_t)(cbase + cc + 0) * DIM + j] = r0;
    out[(size_t)(cbase + cc + 2) * DIM + j] = r1;
    out[(size_t)(cbase + cc + 4) * DIM + j] = r2;
    out[(size_t)(cbase + cc + 6) * DIM + j] = r3;
}

extern "C" void kernel_launch(void* const* d_in, const int* in_sizes, int n_in,
                              void* d_out, int out_size, void* d_ws, size_t ws_size,
                              hipStream_t stream) {
    const float* loc  = (const float*)d_in[0];
    const float* W    = (const float*)d_in[1];
    const float* bias = (const float*)d_in[2];
    const int*   esrc = (const int*)d_in[3];
    const int*   edst = (const int*)d_in[4];
    float* out = (float*)d_out;

    size_t need_cs   = ((size_t)2 * N_EDGES + (size_t)NB * N_CAT + 2 * PAD + DIM * DIM) * sizeof(int);
    size_t need_rank = ((size_t)2 * N_EDGES + 2 * PAD + DIM * DIM) * sizeof(int);

    if (ws_size >= need_cs) {
        int*   rank    = (int*)d_ws;                       // [N_EDGES]
        int*   csr_src = rank + N_EDGES;                   // [N_EDGES]
        int*   bhist   = csr_src + N_EDGES;                // [NB * N_CAT]
        int*   offsets = bhist + (size_t)NB * N_CAT;       // [N_CAT+1] (PAD)
        float* WT      = (float*)(offsets + PAD);          // [DIM*DIM]

        blockhist_kernel<<<NB + 1, 1024, 0, stream>>>(edst, W, WT, rank, bhist);
        fused_scan_kernel<<<1, 1024, 0, stream>>>(bhist, offsets);
        fill2_kernel<<<(N_EDGES / 4 + 255) / 256, 256, 0, stream>>>(esrc, edst, rank, offsets, bhist, csr_src);
        agg_fused_kernel<<<N_CAT, 256, 0, stream>>>(loc, csr_src, offsets, WT, bias, out);
    } else if (ws_size >= need_rank) {
        int* counts  = (int*)d_ws;
        int* offsets = counts + PAD;
        float* WT    = (float*)(offsets + PAD);
        int* rank    = (int*)(WT + DIM * DIM);
        int* csr_src = rank + N_EDGES;

        hipMemsetAsync(counts, 0, (size_t)PAD * sizeof(int), stream);
        transpose_kernel<<<DIM, DIM, 0, stream>>>(W, WT);
        const int eblocks = (N_EDGES + 255) / 256;
        hist_rank_kernel<<<eblocks, 256, 0, stream>>>(edst, counts, rank, N_EDGES);
        scan_kernel<<<1, 1024, 0, stream>>>(counts, offsets);
        fill_rank_kernel<<<eblocks, 256, 0, stream>>>(esrc, edst, rank, offsets, csr_src, N_EDGES);
        agg_fused_kernel<<<N_CAT, 256, 0, stream>>>(loc, csr_src, offsets, WT, bias, out);
    } else {
        int n = N_CAT * DIM;
        zero_kernel<<<(n + 255) / 256, 256, 0, stream>>>(out, n);
        scatter_atomic_kernel<<<N_EDGES, DIM, 0, stream>>>(loc, esrc, edst, out);
        gemm_lrelu_kernel<<<N_CAT / CATS_PER_BLOCK, 256, 0, stream>>>(out, W, bias, out);
    }
}

// Round 6
// 493.364 us; speedup vs baseline: 1.0520x; 1.0520x over previous
//
#include <hip/hip_runtime.h>

#define N_LOC   500000
#define N_CAT   5000
#define N_EDGES 2000000
#define DIM     128
#define NEG_SLOPE 0.2f
#define PAD     5008
#define NB      128
#define EPB     15628   // ceil(N_EDGES/NB) rounded up to multiple of 4

// ================= K1: per-block LDS histogram (+ fused W transpose) =================
__launch_bounds__(1024)
__global__ void blockhist_kernel(const int* __restrict__ edst, const float* __restrict__ W,
                                 float* __restrict__ WT, int* __restrict__ rank,
                                 int* __restrict__ bhist) {
    int b = blockIdx.x, t = threadIdx.x;
    if (b == NB) {  // transpose W -> WT
        for (int i = t; i < DIM * DIM; i += 1024) {
            int j = i >> 7, k = i & 127;
            WT[k * DIM + j] = W[j * DIM + k];
        }
        return;
    }
    __shared__ int lh[N_CAT];
    for (int c = t; c < N_CAT; c += 1024) lh[c] = 0;
    __syncthreads();
    int s = b * EPB;
    int e = min(s + EPB, N_EDGES);
    int i = s + 4 * t;
    for (; i + 4 <= e; i += 4096) {
        int4 d = *(const int4*)(edst + i);
        int4 r;
        r.x = atomicAdd(&lh[d.x], 1);
        r.y = atomicAdd(&lh[d.y], 1);
        r.z = atomicAdd(&lh[d.z], 1);
        r.w = atomicAdd(&lh[d.w], 1);
        *(int4*)(rank + i) = r;
    }
    if (i < e) {
        int lim = min(i + 4, e);
        for (int j = i; j < lim; ++j) rank[j] = atomicAdd(&lh[edst[j]], 1);
    }
    __syncthreads();
    for (int c = t; c < N_CAT; c += 1024)
        bhist[(size_t)b * N_CAT + c] = lh[c];
}

// ================= K2: per-cat exclusive prefix over NB block counts (parallel) ==========
__launch_bounds__(256)
__global__ void blockscan_kernel(int* __restrict__ bhist, int* __restrict__ tot) {
    int c = blockIdx.x * 256 + threadIdx.x;
    if (c >= N_CAT) return;
    int run = 0;
    for (int b0 = 0; b0 < NB; b0 += 8) {
        int v0 = bhist[(size_t)(b0 + 0) * N_CAT + c];
        int v1 = bhist[(size_t)(b0 + 1) * N_CAT + c];
        int v2 = bhist[(size_t)(b0 + 2) * N_CAT + c];
        int v3 = bhist[(size_t)(b0 + 3) * N_CAT + c];
        int v4 = bhist[(size_t)(b0 + 4) * N_CAT + c];
        int v5 = bhist[(size_t)(b0 + 5) * N_CAT + c];
        int v6 = bhist[(size_t)(b0 + 6) * N_CAT + c];
        int v7 = bhist[(size_t)(b0 + 7) * N_CAT + c];
        bhist[(size_t)(b0 + 0) * N_CAT + c] = run; run += v0;
        bhist[(size_t)(b0 + 1) * N_CAT + c] = run; run += v1;
        bhist[(size_t)(b0 + 2) * N_CAT + c] = run; run += v2;
        bhist[(size_t)(b0 + 3) * N_CAT + c] = run; run += v3;
        bhist[(size_t)(b0 + 4) * N_CAT + c] = run; run += v4;
        bhist[(size_t)(b0 + 5) * N_CAT + c] = run; run += v5;
        bhist[(size_t)(b0 + 6) * N_CAT + c] = run; run += v6;
        bhist[(size_t)(b0 + 7) * N_CAT + c] = run; run += v7;
    }
    tot[c] = run;
}

// ================= K3: single-block shfl scan of tot (20 KB only) =================
__launch_bounds__(1024)
__global__ void scan_kernel(const int* __restrict__ cnt, int* __restrict__ offsets) {
    __shared__ int wsum[16];
    __shared__ int woff[16];
    __shared__ int total_s, running_s;
    int t = threadIdx.x;
    int lane = t & 63, w = t >> 6;
    if (t == 0) { running_s = 0; offsets[0] = 0; }
    __syncthreads();
    for (int base = 0; base < N_CAT; base += 1024) {
        int i = base + t;
        int v = (i < N_CAT) ? cnt[i] : 0;
        int incl = v;
        #pragma unroll
        for (int off = 1; off < 64; off <<= 1) {
            int x = __shfl_up(incl, off, 64);
            if (lane >= off) incl += x;
        }
        if (lane == 63) wsum[w] = incl;
        __syncthreads();
        if (w == 0 && lane < 16) {
            int s = wsum[lane];
            int e = s;
            #pragma unroll
            for (int off = 1; off < 16; off <<= 1) {
                int x = __shfl_up(e, off, 64);
                if (lane >= off) e += x;
            }
            woff[lane] = e - s;
            if (lane == 15) total_s = e;
        }
        __syncthreads();
        int run = running_s;
        if (i < N_CAT) offsets[i + 1] = run + woff[w] + incl;
        __syncthreads();
        if (t == 0) running_s = run + total_s;
        __syncthreads();
    }
}

// ================= K4: atomic-free scatter fill (int4-vectorized) =================
__global__ void fill2_kernel(const int* __restrict__ esrc, const int* __restrict__ edst,
                             const int* __restrict__ rank, const int* __restrict__ offsets,
                             const int* __restrict__ bhist, int* __restrict__ csr_src) {
    int i4 = (blockIdx.x * blockDim.x + threadIdx.x) * 4;
    if (i4 + 4 <= N_EDGES) {
        int4 c = *(const int4*)(edst + i4);
        int4 s = *(const int4*)(esrc + i4);
        int4 r = *(const int4*)(rank + i4);
        size_t bb = (size_t)(i4 / EPB) * N_CAT;   // EPB mult of 4: chunk never straddles
        csr_src[offsets[c.x] + bhist[bb + c.x] + r.x] = s.x;
        csr_src[offsets[c.y] + bhist[bb + c.y] + r.y] = s.y;
        csr_src[offsets[c.z] + bhist[bb + c.z] + r.z] = s.z;
        csr_src[offsets[c.w] + bhist[bb + c.w] + r.w] = s.w;
    } else {
        for (int i = i4; i < N_EDGES; ++i) {
            int c = edst[i];
            size_t bb = (size_t)(i / EPB) * N_CAT;
            csr_src[offsets[c] + bhist[bb + c] + rank[i]] = esrc[i];
        }
    }
}

// ================= K5: fused aggregate + linear + LeakyReLU =================
// one block per cat; 8 groups x 32 lanes; contiguous csr range per group, unroll x8.
__launch_bounds__(256)
__global__ void agg_fused_kernel(const float* __restrict__ loc, const int* __restrict__ csr_src,
                                 const int* __restrict__ offsets, const float* __restrict__ WT,
                                 const float* __restrict__ bias, float* __restrict__ out) {
    __shared__ float4 sacc[256];   // reused as float sred[1024]
    __shared__ float  srow[DIM];
    int c = blockIdx.x;
    int t = threadIdx.x;
    int g = t >> 5;
    int l = t & 31;
    int beg = offsets[c];
    int end = offsets[c + 1];
    int cnt = end - beg;
    int per = (cnt + 7) >> 3;
    int gbeg = beg + g * per;
    int gend = min(gbeg + per, end);

    float4 a0 = make_float4(0.f, 0.f, 0.f, 0.f);
    float4 a1 = make_float4(0.f, 0.f, 0.f, 0.f);
    float4 a2 = make_float4(0.f, 0.f, 0.f, 0.f);
    float4 a3 = make_float4(0.f, 0.f, 0.f, 0.f);
    int e = gbeg;
    for (; e + 8 <= gend; e += 8) {
        int s0 = csr_src[e + 0], s1 = csr_src[e + 1], s2 = csr_src[e + 2], s3 = csr_src[e + 3];
        int s4 = csr_src[e + 4], s5 = csr_src[e + 5], s6 = csr_src[e + 6], s7 = csr_src[e + 7];
        float4 v0 = ((const float4*)(loc + (size_t)s0 * DIM))[l];
        float4 v1 = ((const float4*)(loc + (size_t)s1 * DIM))[l];
        float4 v2 = ((const float4*)(loc + (size_t)s2 * DIM))[l];
        float4 v3 = ((const float4*)(loc + (size_t)s3 * DIM))[l];
        float4 v4 = ((const float4*)(loc + (size_t)s4 * DIM))[l];
        float4 v5 = ((const float4*)(loc + (size_t)s5 * DIM))[l];
        float4 v6 = ((const float4*)(loc + (size_t)s6 * DIM))[l];
        float4 v7 = ((const float4*)(loc + (size_t)s7 * DIM))[l];
        a0.x += v0.x; a0.y += v0.y; a0.z += v0.z; a0.w += v0.w;
        a1.x += v1.x; a1.y += v1.y; a1.z += v1.z; a1.w += v1.w;
        a2.x += v2.x; a2.y += v2.y; a2.z += v2.z; a2.w += v2.w;
        a3.x += v3.x; a3.y += v3.y; a3.z += v3.z; a3.w += v3.w;
        a0.x += v4.x; a0.y += v4.y; a0.z += v4.z; a0.w += v4.w;
        a1.x += v5.x; a1.y += v5.y; a1.z += v5.z; a1.w += v5.w;
        a2.x += v6.x; a2.y += v6.y; a2.z += v6.z; a2.w += v6.w;
        a3.x += v7.x; a3.y += v7.y; a3.z += v7.z; a3.w += v7.w;
    }
    for (; e + 4 <= gend; e += 4) {
        int s0 = csr_src[e + 0], s1 = csr_src[e + 1], s2 = csr_src[e + 2], s3 = csr_src[e + 3];
        float4 v0 = ((const float4*)(loc + (size_t)s0 * DIM))[l];
        float4 v1 = ((const float4*)(loc + (size_t)s1 * DIM))[l];
        float4 v2 = ((const float4*)(loc + (size_t)s2 * DIM))[l];
        float4 v3 = ((const float4*)(loc + (size_t)s3 * DIM))[l];
        a0.x += v0.x; a0.y += v0.y; a0.z += v0.z; a0.w += v0.w;
        a1.x += v1.x; a1.y += v1.y; a1.z += v1.z; a1.w += v1.w;
        a2.x += v2.x; a2.y += v2.y; a2.z += v2.z; a2.w += v2.w;
        a3.x += v3.x; a3.y += v3.y; a3.z += v3.z; a3.w += v3.w;
    }
    for (; e < gend; ++e) {
        int s = csr_src[e];
        float4 v = ((const float4*)(loc + (size_t)s * DIM))[l];
        a0.x += v.x; a0.y += v.y; a0.z += v.z; a0.w += v.w;
    }
    float4 acc = make_float4((a0.x + a1.x) + (a2.x + a3.x),
                             (a0.y + a1.y) + (a2.y + a3.y),
                             (a0.z + a1.z) + (a2.z + a3.z),
                             (a0.w + a1.w) + (a2.w + a3.w));
    sacc[t] = acc;
    __syncthreads();
    if (t < 128) {
        float4 a = sacc[t], b = sacc[t + 128];
        sacc[t] = make_float4(a.x + b.x, a.y + b.y, a.z + b.z, a.w + b.w);
    }
    __syncthreads();
    if (t < 64) {
        float4 a = sacc[t], b = sacc[t + 64];
        sacc[t] = make_float4(a.x + b.x, a.y + b.y, a.z + b.z, a.w + b.w);
    }
    __syncthreads();
    if (t < 32) {
        float4 a = sacc[t], b = sacc[t + 32];
        srow[4 * t + 0] = a.x + b.x;
        srow[4 * t + 1] = a.y + b.y;
        srow[4 * t + 2] = a.z + b.z;
        srow[4 * t + 3] = a.w + b.w;
    }
    __syncthreads();
    int j = t & 127;
    int h = t >> 7;
    float m0 = 0.f, m1 = 0.f, m2 = 0.f, m3 = 0.f;
    int k0 = h * 64;
    #pragma unroll 4
    for (int k = 0; k < 64; k += 4) {
        m0 += WT[(k0 + k + 0) * DIM + j] * srow[k0 + k + 0];
        m1 += WT[(k0 + k + 1) * DIM + j] * srow[k0 + k + 1];
        m2 += WT[(k0 + k + 2) * DIM + j] * srow[k0 + k + 2];
        m3 += WT[(k0 + k + 3) * DIM + j] * srow[k0 + k + 3];
    }
    float* sred = (float*)sacc;
    sred[t] = (m0 + m1) + (m2 + m3);
    __syncthreads();
    if (t < 128) {
        float v = sred[t] + sred[t + 128] + bias[t];
        v = v > 0.f ? v : NEG_SLOPE * v;
        out[(size_t)c * DIM + t] = v;
    }
}

// ================= fallback paths =================

__global__ void hist_rank_kernel(const int* __restrict__ dst, int* __restrict__ cnt,
                                 int* __restrict__ rank, int n) {
    int i = blockIdx.x * blockDim.x + threadIdx.x;
    if (i < n) rank[i] = atomicAdd(&cnt[dst[i]], 1);
}

__global__ void fill_rank_kernel(const int* __restrict__ src, const int* __restrict__ dst,
                                 const int* __restrict__ rank, const int* __restrict__ offsets,
                                 int* __restrict__ csr_src, int n) {
    int i = blockIdx.x * blockDim.x + threadIdx.x;
    if (i < n) csr_src[offsets[dst[i]] + rank[i]] = src[i];
}

__global__ void transpose_kernel(const float* __restrict__ W, float* __restrict__ WT) {
    int j = blockIdx.x;
    int k = threadIdx.x;
    WT[k * DIM + j] = W[j * DIM + k];
}

__global__ void zero_kernel(float* p, int n) {
    int i = blockIdx.x * blockDim.x + threadIdx.x;
    if (i < n) p[i] = 0.f;
}

__launch_bounds__(128)
__global__ void scatter_atomic_kernel(const float* __restrict__ loc, const int* __restrict__ src,
                                      const int* __restrict__ dst, float* __restrict__ agg) {
    int e = blockIdx.x;
    int d = threadIdx.x;
    atomicAdd(&agg[(size_t)dst[e] * DIM + d], loc[(size_t)src[e] * DIM + d]);
}

#define CATS_PER_BLOCK 8
__launch_bounds__(256)
__global__ void gemm_lrelu_kernel(const float* __restrict__ agg, const float* __restrict__ W,
                                  const float* __restrict__ b, float* __restrict__ out) {
    __shared__ float sW[DIM * 129];
    __shared__ float sA[CATS_PER_BLOCK * DIM];
    int t = threadIdx.x;
    int cbase = blockIdx.x * CATS_PER_BLOCK;
    for (int i = t; i < DIM * DIM; i += 256) {
        int j = i >> 7, k = i & 127;
        sW[j * 129 + k] = W[i];
    }
    for (int i = t; i < CATS_PER_BLOCK * DIM; i += 256)
        sA[i] = agg[(size_t)cbase * DIM + i];
    __syncthreads();
    int j = t & 127;
    int cc = t >> 7;
    float acc0 = 0.f, acc1 = 0.f, acc2 = 0.f, acc3 = 0.f;
    for (int k = 0; k < DIM; ++k) {
        float w = sW[j * 129 + k];
        acc0 += w * sA[(cc + 0) * DIM + k];
        acc1 += w * sA[(cc + 2) * DIM + k];
        acc2 += w * sA[(cc + 4) * DIM + k];
        acc3 += w * sA[(cc + 6) * DIM + k];
    }
    float bj = b[j];
    float r0 = acc0 + bj, r1 = acc1 + bj, r2 = acc2 + bj, r3 = acc3 + bj;
    r0 = r0 > 0.f ? r0 : NEG_SLOPE * r0;
    r1 = r1 > 0.f ? r1 : NEG_SLOPE * r1;
    r2 = r2 > 0.f ? r2 : NEG_SLOPE * r2;
    r3 = r3 > 0.f ? r3 : NEG_SLOPE * r3;
    out[(size_t)(cbase + cc + 0) * DIM + j] = r0;
    out[(size_t)(cbase + cc + 2) * DIM + j] = r1;
    out[(size_t)(cbase + cc + 4) * DIM + j] = r2;
    out[(size_t)(cbase + cc + 6) * DIM + j] = r3;
}

extern "C" void kernel_launch(void* const* d_in, const int* in_sizes, int n_in,
                              void* d_out, int out_size, void* d_ws, size_t ws_size,
                              hipStream_t stream) {
    const float* loc  = (const float*)d_in[0];
    const float* W    = (const float*)d_in[1];
    const float* bias = (const float*)d_in[2];
    const int*   esrc = (const int*)d_in[3];
    const int*   edst = (const int*)d_in[4];
    float* out = (float*)d_out;

    size_t need_cs   = ((size_t)2 * N_EDGES + (size_t)NB * N_CAT + 3 * PAD + DIM * DIM) * sizeof(int);
    size_t need_rank = ((size_t)2 * N_EDGES + 2 * PAD + DIM * DIM) * sizeof(int);

    if (ws_size >= need_cs) {
        int*   rank    = (int*)d_ws;                       // [N_EDGES]
        int*   csr_src = rank + N_EDGES;                   // [N_EDGES]
        int*   bhist   = csr_src + N_EDGES;                // [NB * N_CAT]
        int*   tot     = bhist + (size_t)NB * N_CAT;       // [PAD]
        int*   offsets = tot + PAD;                        // [N_CAT+1] (PAD)
        float* WT      = (float*)(offsets + PAD);          // [DIM*DIM]

        blockhist_kernel<<<NB + 1, 1024, 0, stream>>>(edst, W, WT, rank, bhist);
        blockscan_kernel<<<(N_CAT + 255) / 256, 256, 0, stream>>>(bhist, tot);
        scan_kernel<<<1, 1024, 0, stream>>>(tot, offsets);
        fill2_kernel<<<(N_EDGES / 4 + 255) / 256, 256, 0, stream>>>(esrc, edst, rank, offsets, bhist, csr_src);
        agg_fused_kernel<<<N_CAT, 256, 0, stream>>>(loc, csr_src, offsets, WT, bias, out);
    } else if (ws_size >= need_rank) {
        int* counts  = (int*)d_ws;
        int* offsets = counts + PAD;
        float* WT    = (float*)(offsets + PAD);
        int* rank    = (int*)(WT + DIM * DIM);
        int* csr_src = rank + N_EDGES;

        hipMemsetAsync(counts, 0, (size_t)PAD * sizeof(int), stream);
        transpose_kernel<<<DIM, DIM, 0, stream>>>(W, WT);
        const int eblocks = (N_EDGES + 255) / 256;
        hist_rank_kernel<<<eblocks, 256, 0, stream>>>(edst, counts, rank, N_EDGES);
        scan_kernel<<<1, 1024, 0, stream>>>(counts, offsets);
        fill_rank_kernel<<<eblocks, 256, 0, stream>>>(esrc, edst, rank, offsets, csr_src, N_EDGES);
        agg_fused_kernel<<<N_CAT, 256, 0, stream>>>(loc, csr_src, offsets, WT, bias, out);
    } else {
        int n = N_CAT * DIM;
        zero_kernel<<<(n + 255) / 256, 256, 0, stream>>>(out, n);
        scatter_atomic_kernel<<<N_EDGES, DIM, 0, stream>>>(loc, esrc, edst, out);
        gemm_lrelu_kernel<<<N_CAT / CATS_PER_BLOCK, 256, 0, stream>>>(out, W, bias, out);
    }
}